// Round 6
// baseline (206.782 us; speedup 1.0000x reference)
//
#include <hip/hip_runtime.h>

#define HW 1659      // 21*79
#define PADID 4096
#define EMB 20
#define HID 32
#define MAXLEN 64
#define PROJ_BLOCKS 128

typedef float v2f __attribute__((ext_vector_type(2)));

// DPP lane-permute helper (pure VALU, no LDS pipe). CTRL is an immediate.
template <int CTRL>
__device__ __forceinline__ float dppf(float v) {
    return __builtin_bit_cast(float,
        __builtin_amdgcn_update_dpp(0, __builtin_bit_cast(int, v),
                                    CTRL, 0xF, 0xF, true));
}
#define DPP_XOR1 0xB1   // quad_perm [1,0,3,2]
#define DPP_XOR2 0x4E   // quad_perm [2,3,0,1]
#define DPP_XOR7 0x141  // row_half_mirror (xor 7 within 16)
#define DPP_XORF 0x140  // row_mirror      (xor 15 within 16)

// ---------------- Kernel 1: 128-thread block-per-sample bag+emb (stable 46us) --
__global__ __launch_bounds__(128, 4) void bag_emb_kernel(
    const int* __restrict__ chars, const int* __restrict__ colors,
    const float* __restrict__ emb_table, const float* __restrict__ W_ih,
    float* __restrict__ out_emb, float* __restrict__ out_bag,
    float* __restrict__ proj, int nbag)
{
    const int tid = threadIdx.x;

    if ((int)blockIdx.x >= nbag) {
        // ---- proj tail blocks: proj[g][j] = emb_table[g] . W_ih[j] ----
        const int gid = ((int)blockIdx.x - nbag) * 128 + tid;
        const int NP = (PADID + 1) * HID;          // 131104
        for (int idx = gid; idx < NP; idx += PROJ_BLOCKS * 128) {
            const int g = idx >> 5, j = idx & 31;
            const float* er = emb_table + (size_t)g * EMB;
            const float* wr = W_ih + j * EMB;
            float s = 0.f;
#pragma unroll
            for (int k = 0; k < EMB; k++) s += wr[k] * er[k];
            proj[idx] = s;
        }
        return;
    }

    __shared__ __align__(16) unsigned char pres[4096];
    __shared__ int bagl[64];
    __shared__ int wsum[2];

    const int lane = tid & 63;
    const int wv   = tid >> 6;
    const int b    = blockIdx.x;

    const int base = b * HW;
    const int pe = (4 - (base & 3)) & 3;          // peel to 16B alignment
    const int nv = (HW - pe) >> 2;                // always 414 int4 groups
    const int nt = HW - pe - (nv << 2);           // tail 0..3
    const int4* c4 = (const int4*)(chars + base + pe);
    const int4* k4 = (const int4*)(colors + base + pe);

    // ---- hoist ALL loads up front (8 int4 = 32 VGPRs, independent) ----
    int4 ca0 = c4[tid],       ka0 = k4[tid];
    int4 ca1 = c4[tid + 128], ka1 = k4[tid + 128];
    int4 ca2 = c4[tid + 256], ka2 = k4[tid + 256];     // 383 < 414 always
    const bool has3 = (tid + 384) < nv;                // tid < 30
    const int i3 = has3 ? tid + 384 : tid;
    int4 ca3 = c4[i3], ka3 = k4[i3];
    int gp = -1, gt = -1;
    if (tid < pe) gp = (chars[base + tid] << 4) + colors[base + tid];
    if (tid < nt) {
        const int i = base + pe + (nv << 2) + tid;
        gt = (chars[i] << 4) + colors[i];
    }

    // zero presence map: 256 uint4 over 128 threads
    ((uint4*)pres)[tid]       = make_uint4(0u, 0u, 0u, 0u);
    ((uint4*)pres)[tid + 128] = make_uint4(0u, 0u, 0u, 0u);
    if (tid < 64) bagl[tid] = PADID;
    __syncthreads();

    pres[(ca0.x << 4) + ka0.x] = 1;
    pres[(ca0.y << 4) + ka0.y] = 1;
    pres[(ca0.z << 4) + ka0.z] = 1;
    pres[(ca0.w << 4) + ka0.w] = 1;
    pres[(ca1.x << 4) + ka1.x] = 1;
    pres[(ca1.y << 4) + ka1.y] = 1;
    pres[(ca1.z << 4) + ka1.z] = 1;
    pres[(ca1.w << 4) + ka1.w] = 1;
    pres[(ca2.x << 4) + ka2.x] = 1;
    pres[(ca2.y << 4) + ka2.y] = 1;
    pres[(ca2.z << 4) + ka2.z] = 1;
    pres[(ca2.w << 4) + ka2.w] = 1;
    if (has3) {
        pres[(ca3.x << 4) + ka3.x] = 1;
        pres[(ca3.y << 4) + ka3.y] = 1;
        pres[(ca3.z << 4) + ka3.z] = 1;
        pres[(ca3.w << 4) + ka3.w] = 1;
    }
    if (gp >= 0) pres[gp] = 1;
    if (gt >= 0) pres[gt] = 1;
    __syncthreads();

    // ---- round-based readback: round r covers ids [2048r, 2048r+2048) ----
    const unsigned M = 0x01010101u;
    int base_cnt = 0;
#pragma unroll 1
    for (int r = 0; r < 2; r++) {
        const uint4 w = ((const uint4*)pres)[tid + (r << 7)];
        const int cnt = __popc(w.x & M) + __popc(w.y & M)
                      + __popc(w.z & M) + __popc(w.w & M);
        int pre = cnt;
#pragma unroll
        for (int d = 1; d < 64; d <<= 1) {
            const int v = __shfl_up(pre, d, 64);
            if (lane >= d) pre += v;
        }
        if (lane == 63) wsum[wv] = pre;
        __syncthreads();
        const int w0 = wsum[0], w1 = wsum[1];
        int p = base_cnt + (wv ? w0 : 0) + pre - cnt;     // exclusive prefix
        if (p < 64) {
            const unsigned wrd[4] = {w.x, w.y, w.z, w.w};
            const int idbase = (r << 11) + (tid << 4);
#pragma unroll
            for (int c = 0; c < 4; c++) {
#pragma unroll
                for (int k = 0; k < 4; k++) {
                    if ((wrd[c] >> (8 * k)) & 1) {
                        if (p < 64) bagl[p] = idbase + 4 * c + k;
                        p++;
                    }
                }
            }
        }
        base_cnt += w0 + w1;                 // block-uniform running total
        if (base_cnt >= 64) break;           // bag full -> skip round 1
        __syncthreads();                     // rare path: protect wsum reuse
    }
    __syncthreads();                         // bagl ready

    if (tid < 64) out_bag[(size_t)b * 64 + tid] = (float)bagl[tid];

    // gather embedding rows: 320 float4 over 128 threads, coalesced writes
    const float4* tab4 = (const float4*)emb_table;
    float4* dst4 = (float4*)(out_emb + (size_t)b * (MAXLEN * EMB));
#pragma unroll
    for (int m = 0; m < 3; m++) {
        const int q = tid + (m << 7);
        if (q < MAXLEN * 5) {
            const int t = q / 5;
            const int mm = q - t * 5;
            const int row = bagl[t];
            dst4[q] = tab4[row * 5 + mm];
        }
    }
}

// ------------------- Kernel 2: packed RNN, LDS-STAGED pv ---------------------
// R0-R5 ledger: rnn stuck at 102-114us across looped/unrolled/pinned/pipelined
// variants (VALUBusy ~19.5% -> ~80% stall). Only surviving memory hypothesis:
// per-step pv/idx gathers are sunk to point-of-use (VGPR 88/104 << live set
// needed for prefetch) and each exposes L3/HBM latency serially; every
// source-level prefetch was defeated by the compiler. This version is immune
// by construction: ALL 64 steps' pv pairs are staged to LDS up front with
// 128 fire-and-forget global_load_lds (per-lane global src + wave-uniform LDS
// dst, 4B each), ONE vmcnt(0) drain, then the compute loop touches only LDS
// (stride-1 conflict-free ds_read_b32, compiler pipelines lgkmcnt). 1 wave
// per block -> zero barriers. LDS 32KB/block -> ~5 blocks/CU.
// DISCRIMINATOR: if rnn still >=80us with zero global traffic in the compute
// phase, memory is exonerated -> limiter is issue/clock/serial-chain.

__device__ __forceinline__ void rnn_step(
    bool upd, v2f pv,
    const v2f (&w0)[16], const v2f (&w1)[16],
    float sb0, float sb1, float& h0, float& h1)
{
    // ---- DPP butterfly all-gather: g[m] = pair (jj ^ GMAP[m]) ----
    v2f g[16];
    g[0] = (v2f){h0, h1};
    g[1] = (v2f){dppf<DPP_XOR1>(g[0][0]), dppf<DPP_XOR1>(g[0][1])};
    g[2] = (v2f){dppf<DPP_XOR2>(g[0][0]), dppf<DPP_XOR2>(g[0][1])};
    g[3] = (v2f){dppf<DPP_XOR2>(g[1][0]), dppf<DPP_XOR2>(g[1][1])};
#pragma unroll
    for (int m = 0; m < 4; m++)
        g[4 + m] = (v2f){dppf<DPP_XOR7>(g[m][0]), dppf<DPP_XOR7>(g[m][1])};
#pragma unroll
    for (int m = 0; m < 8; m++)
        g[8 + m] = (v2f){dppf<DPP_XORF>(g[m][0]), dppf<DPP_XORF>(g[m][1])};

    // ---- 32 pk_fma: rows 2jj and 2jj+1 ----
    v2f a0 = (v2f){0.f, 0.f}, b0 = a0, a1 = a0, b1 = a0;
#pragma unroll
    for (int m = 0; m < 16; m += 2) {
        a0 = __builtin_elementwise_fma(w0[m],     g[m],     a0);
        b0 = __builtin_elementwise_fma(w0[m + 1], g[m + 1], b0);
        a1 = __builtin_elementwise_fma(w1[m],     g[m],     a1);
        b1 = __builtin_elementwise_fma(w1[m + 1], g[m + 1], b1);
    }
    float s0 = sb0 + pv[0] + (a0[0] + a0[1]) + (b0[0] + b0[1]);
    float s1 = sb1 + pv[1] + (a1[0] + a1[1]) + (b1[0] + b1[1]);

    // tanh(s) = 1 - 2/(e^{2s}+1); robust at both extremes, no clamp
    float e0 = __expf(2.f * s0);
    float e1 = __expf(2.f * s1);
    float th0 = 1.f - 2.f * __builtin_amdgcn_rcpf(e0 + 1.f);
    float th1 = 1.f - 2.f * __builtin_amdgcn_rcpf(e1 + 1.f);

    h0 = upd ? th0 : h0;
    h1 = upd ? th1 : h1;
}

__global__ __launch_bounds__(64, 2)
void rnn_kernel(
    const float* __restrict__ proj, const float* __restrict__ bagf,
    const float* __restrict__ W_hh,
    const float* __restrict__ b_ih, const float* __restrict__ b_hh,
    float* __restrict__ out_h)
{
    __shared__ float pvx[MAXLEN * 64];     // [t][lane], 16 KB
    __shared__ float pvy[MAXLEN * 64];     // [t][lane], 16 KB

    const int lane = threadIdx.x & 63;
    const int sl   = lane >> 4;        // sample slot within wave 0..3
    const int jj   = lane & 15;        // owns hidden units 2jj, 2jj+1
    const int b    = blockIdx.x * 4 + sl;

    // gather-position -> pair-xor map (butterfly: xor1, xor2, xor7, xor15)
    const int GMAP[16] = {0,1,2,3, 7,6,5,4, 15,14,13,12,11,10,9,8};

    // weights: w0[m]/w1[m] = rows (2jj, 2jj+1), column pair c = jj ^ GMAP[m]
    v2f w0[16], w1[16];
    const v2f* wr0 = (const v2f*)(W_hh + (2 * jj) * HID);
    const v2f* wr1 = (const v2f*)(W_hh + (2 * jj + 1) * HID);
#pragma unroll
    for (int m = 0; m < 16; m++) {
        const int c = jj ^ GMAP[m];
        w0[m] = wr0[c];
        w1[m] = wr1[c];
    }
    const float sb0 = b_ih[2 * jj]     + b_hh[2 * jj];
    const float sb1 = b_ih[2 * jj + 1] + b_hh[2 * jj + 1];

    const float* bps = bagf + (size_t)b * 64;

    // ---- stage ALL 64 steps' pv pairs into LDS (fire-and-forget) ----
    // lane writes pvx[t*64+lane] = proj[row*32 + 2jj], pvy[...] = [... + 2jj+1]
    // (PAD rows map to proj row 4096 which is all-zero -> safe to stage.)
    int len = 0;
#pragma unroll 1
    for (int ch = 0; ch < 4; ++ch) {
        float id16[16];
#pragma unroll
        for (int i = 0; i < 16; ++i) id16[i] = bps[ch * 16 + i];
#pragma unroll
        for (int i = 0; i < 16; ++i) {
            const int t   = ch * 16 + i;
            const int row = (int)id16[i];           // 0..4096, exact in f32
            len += (row < PADID) ? 1 : 0;
            const float* src = proj + row * HID + (jj << 1);
            __builtin_amdgcn_global_load_lds(
                (const __attribute__((address_space(1))) void*)src,
                (__attribute__((address_space(3))) void*)&pvx[t << 6],
                4, 0, 0);
            __builtin_amdgcn_global_load_lds(
                (const __attribute__((address_space(1))) void*)src,
                (__attribute__((address_space(3))) void*)&pvy[t << 6],
                4, 4, 0);
        }
    }
    asm volatile("s_waitcnt vmcnt(0)" ::: "memory");
    // single wave per block: own LDS writes now visible, no barrier needed

    float h0 = 0.f, h1 = 0.f;
#pragma unroll 4
    for (int t = 0; t < MAXLEN; ++t) {
        const v2f pv = (v2f){ pvx[(t << 6) + lane], pvy[(t << 6) + lane] };
        rnn_step(t < len, pv, w0, w1, sb0, sb1, h0, h1);
    }

    ((float2*)(out_h + (size_t)b * HID))[jj] = make_float2(h0, h1);
}

// ---------------- Fallback RNN (R4 exact) if ws can't hold proj ----------------
__global__ __launch_bounds__(128, 4) void rnn_kernel_noproj(
    const float* __restrict__ emb, const float* __restrict__ bagf,
    const float* __restrict__ W_ih, const float* __restrict__ W_hh,
    const float* __restrict__ b_ih, const float* __restrict__ b_hh,
    float* __restrict__ out_h)
{
    __shared__ float hbuf[4][32];
    const int tid = threadIdx.x;
    const int ib  = tid >> 5;
    const int j   = tid & 31;
    const int b   = blockIdx.x * 4 + ib;

    float wih[EMB];
#pragma unroll
    for (int k = 0; k < EMB; k++) wih[k] = W_ih[j * EMB + k];
    float whh[HID];
#pragma unroll
    for (int k = 0; k < HID; k++) whh[k] = W_hh[j * HID + k];
    const float sbias = b_ih[j] + b_hh[j];

    const float* bp = bagf + (size_t)b * 64;
    unsigned long long m0 = __ballot(bp[j]      < 4095.5f);
    unsigned long long m1 = __ballot(bp[32 + j] < 4095.5f);
    const int half = ib & 1;
    const int len = __popc((unsigned)(m0 >> (half * 32)))
                  + __popc((unsigned)(m1 >> (half * 32)));

    hbuf[ib][j] = 0.f;
    asm volatile("s_waitcnt lgkmcnt(0)" ::: "memory");

    float h = 0.f;
    const float* xb = emb + (size_t)b * (MAXLEN * EMB);
    for (int t = 0; t < MAXLEN; t++) {
        const float4* xp = (const float4*)(xb + t * EMB);
        float4 x0 = xp[0], x1 = xp[1], x2 = xp[2], x3 = xp[3], x4 = xp[4];
        float s = sbias;
        const float4* hb4 = (const float4*)hbuf[ib];
#pragma unroll
        for (int m = 0; m < 8; m++) {
            float4 hv = hb4[m];
            s += whh[4*m+0]*hv.x + whh[4*m+1]*hv.y
               + whh[4*m+2]*hv.z + whh[4*m+3]*hv.w;
        }
        s += wih[0]*x0.x + wih[1]*x0.y + wih[2]*x0.z + wih[3]*x0.w;
        s += wih[4]*x1.x + wih[5]*x1.y + wih[6]*x1.z + wih[7]*x1.w;
        s += wih[8]*x2.x + wih[9]*x2.y + wih[10]*x2.z + wih[11]*x2.w;
        s += wih[12]*x3.x + wih[13]*x3.y + wih[14]*x3.z + wih[15]*x3.w;
        s += wih[16]*x4.x + wih[17]*x4.y + wih[18]*x4.z + wih[19]*x4.w;
        s = fminf(fmaxf(s, -9.f), 9.f);
        float e = __expf(2.f * s);
        float th = (e - 1.f) * __builtin_amdgcn_rcpf(e + 1.f);
        h = (t < len) ? th : h;
        hbuf[ib][j] = h;
        asm volatile("s_waitcnt lgkmcnt(0)" ::: "memory");
    }
    out_h[(size_t)b * HID + j] = h;
}

extern "C" void kernel_launch(void* const* d_in, const int* in_sizes, int n_in,
                              void* d_out, int out_size, void* d_ws, size_t ws_size,
                              hipStream_t stream) {
    const int*   chars     = (const int*)d_in[0];
    const int*   colors    = (const int*)d_in[1];
    const float* emb_table = (const float*)d_in[2];
    const float* W_ih      = (const float*)d_in[3];
    const float* W_hh      = (const float*)d_in[4];
    const float* b_ih      = (const float*)d_in[5];
    const float* b_hh      = (const float*)d_in[6];

    const int B = in_sizes[0] / HW;      // 8192

    float* out     = (float*)d_out;
    float* out_h   = out;                                    // [B, 32]
    float* out_emb = out + (size_t)B * HID;                  // [B, 64, 20]
    float* out_bag = out_emb + (size_t)B * MAXLEN * EMB;     // [B, 64]

    const size_t proj_bytes = (size_t)(PADID + 1) * HID * sizeof(float);

    if (ws_size >= proj_bytes && (B % 4) == 0) {   // ws_size fixed -> same path every call
        float* proj = (float*)d_ws;
        bag_emb_kernel<<<B + PROJ_BLOCKS, 128, 0, stream>>>(
            chars, colors, emb_table, W_ih, out_emb, out_bag, proj, B);
        rnn_kernel<<<B / 4, 64, 0, stream>>>(proj, out_bag, W_hh, b_ih, b_hh, out_h);
    } else {
        bag_emb_kernel<<<B, 128, 0, stream>>>(
            chars, colors, emb_table, W_ih, out_emb, out_bag, (float*)d_ws, B);
        rnn_kernel_noproj<<<B / 4, 128, 0, stream>>>(out_emb, out_bag, W_ih, W_hh,
                                                     b_ih, b_hh, out_h);
    }
}

// Round 7
// 185.373 us; speedup vs baseline: 1.1155x; 1.1155x over previous
//
#include <hip/hip_runtime.h>

#define HW 1659      // 21*79
#define PADID 4096
#define EMB 20
#define HID 32
#define MAXLEN 64
#define PROJ_BLOCKS 128

typedef float v2f __attribute__((ext_vector_type(2)));

// DPP lane-permute helper (pure VALU, no LDS pipe). CTRL is an immediate.
template <int CTRL>
__device__ __forceinline__ float dppf(float v) {
    return __builtin_bit_cast(float,
        __builtin_amdgcn_update_dpp(0, __builtin_bit_cast(int, v),
                                    CTRL, 0xF, 0xF, true));
}
#define DPP_XOR1 0xB1   // quad_perm [1,0,3,2]
#define DPP_XOR2 0x4E   // quad_perm [2,3,0,1]
#define DPP_XOR7 0x141  // row_half_mirror (xor 7 within 16)
#define DPP_XORF 0x140  // row_mirror      (xor 15 within 16)

// ---------------- Kernel 1: 128-thread block-per-sample bag+emb (stable 46us) --
__global__ __launch_bounds__(128, 4) void bag_emb_kernel(
    const int* __restrict__ chars, const int* __restrict__ colors,
    const float* __restrict__ emb_table, const float* __restrict__ W_ih,
    float* __restrict__ out_emb, float* __restrict__ out_bag,
    float* __restrict__ proj, int nbag)
{
    const int tid = threadIdx.x;

    if ((int)blockIdx.x >= nbag) {
        // ---- proj tail blocks: proj[g][j] = emb_table[g] . W_ih[j] ----
        const int gid = ((int)blockIdx.x - nbag) * 128 + tid;
        const int NP = (PADID + 1) * HID;          // 131104
        for (int idx = gid; idx < NP; idx += PROJ_BLOCKS * 128) {
            const int g = idx >> 5, j = idx & 31;
            const float* er = emb_table + (size_t)g * EMB;
            const float* wr = W_ih + j * EMB;
            float s = 0.f;
#pragma unroll
            for (int k = 0; k < EMB; k++) s += wr[k] * er[k];
            proj[idx] = s;
        }
        return;
    }

    __shared__ __align__(16) unsigned char pres[4096];
    __shared__ int bagl[64];
    __shared__ int wsum[2];

    const int lane = tid & 63;
    const int wv   = tid >> 6;
    const int b    = blockIdx.x;

    const int base = b * HW;
    const int pe = (4 - (base & 3)) & 3;          // peel to 16B alignment
    const int nv = (HW - pe) >> 2;                // always 414 int4 groups
    const int nt = HW - pe - (nv << 2);           // tail 0..3
    const int4* c4 = (const int4*)(chars + base + pe);
    const int4* k4 = (const int4*)(colors + base + pe);

    // ---- hoist ALL loads up front (8 int4 = 32 VGPRs, independent) ----
    int4 ca0 = c4[tid],       ka0 = k4[tid];
    int4 ca1 = c4[tid + 128], ka1 = k4[tid + 128];
    int4 ca2 = c4[tid + 256], ka2 = k4[tid + 256];     // 383 < 414 always
    const bool has3 = (tid + 384) < nv;                // tid < 30
    const int i3 = has3 ? tid + 384 : tid;
    int4 ca3 = c4[i3], ka3 = k4[i3];
    int gp = -1, gt = -1;
    if (tid < pe) gp = (chars[base + tid] << 4) + colors[base + tid];
    if (tid < nt) {
        const int i = base + pe + (nv << 2) + tid;
        gt = (chars[i] << 4) + colors[i];
    }

    // zero presence map: 256 uint4 over 128 threads
    ((uint4*)pres)[tid]       = make_uint4(0u, 0u, 0u, 0u);
    ((uint4*)pres)[tid + 128] = make_uint4(0u, 0u, 0u, 0u);
    if (tid < 64) bagl[tid] = PADID;
    __syncthreads();

    pres[(ca0.x << 4) + ka0.x] = 1;
    pres[(ca0.y << 4) + ka0.y] = 1;
    pres[(ca0.z << 4) + ka0.z] = 1;
    pres[(ca0.w << 4) + ka0.w] = 1;
    pres[(ca1.x << 4) + ka1.x] = 1;
    pres[(ca1.y << 4) + ka1.y] = 1;
    pres[(ca1.z << 4) + ka1.z] = 1;
    pres[(ca1.w << 4) + ka1.w] = 1;
    pres[(ca2.x << 4) + ka2.x] = 1;
    pres[(ca2.y << 4) + ka2.y] = 1;
    pres[(ca2.z << 4) + ka2.z] = 1;
    pres[(ca2.w << 4) + ka2.w] = 1;
    if (has3) {
        pres[(ca3.x << 4) + ka3.x] = 1;
        pres[(ca3.y << 4) + ka3.y] = 1;
        pres[(ca3.z << 4) + ka3.z] = 1;
        pres[(ca3.w << 4) + ka3.w] = 1;
    }
    if (gp >= 0) pres[gp] = 1;
    if (gt >= 0) pres[gt] = 1;
    __syncthreads();

    // ---- round-based readback: round r covers ids [2048r, 2048r+2048) ----
    const unsigned M = 0x01010101u;
    int base_cnt = 0;
#pragma unroll 1
    for (int r = 0; r < 2; r++) {
        const uint4 w = ((const uint4*)pres)[tid + (r << 7)];
        const int cnt = __popc(w.x & M) + __popc(w.y & M)
                      + __popc(w.z & M) + __popc(w.w & M);
        int pre = cnt;
#pragma unroll
        for (int d = 1; d < 64; d <<= 1) {
            const int v = __shfl_up(pre, d, 64);
            if (lane >= d) pre += v;
        }
        if (lane == 63) wsum[wv] = pre;
        __syncthreads();
        const int w0 = wsum[0], w1 = wsum[1];
        int p = base_cnt + (wv ? w0 : 0) + pre - cnt;     // exclusive prefix
        if (p < 64) {
            const unsigned wrd[4] = {w.x, w.y, w.z, w.w};
            const int idbase = (r << 11) + (tid << 4);
#pragma unroll
            for (int c = 0; c < 4; c++) {
#pragma unroll
                for (int k = 0; k < 4; k++) {
                    if ((wrd[c] >> (8 * k)) & 1) {
                        if (p < 64) bagl[p] = idbase + 4 * c + k;
                        p++;
                    }
                }
            }
        }
        base_cnt += w0 + w1;                 // block-uniform running total
        if (base_cnt >= 64) break;           // bag full -> skip round 1
        __syncthreads();                     // rare path: protect wsum reuse
    }
    __syncthreads();                         // bagl ready

    if (tid < 64) out_bag[(size_t)b * 64 + tid] = (float)bagl[tid];

    // gather embedding rows: 320 float4 over 128 threads, coalesced writes
    const float4* tab4 = (const float4*)emb_table;
    float4* dst4 = (float4*)(out_emb + (size_t)b * (MAXLEN * EMB));
#pragma unroll
    for (int m = 0; m < 3; m++) {
        const int q = tid + (m << 7);
        if (q < MAXLEN * 5) {
            const int t = q / 5;
            const int mm = q - t * 5;
            const int row = bagl[t];
            dst4[q] = tab4[row * 5 + mm];
        }
    }
}

// -------- Kernel 2: packed RNN, chunked LDS staging + counted vmcnt -----------
// R6 proved per-step pv latency was the stall (102->60us via LDS staging) but
// kept occupancy at 2.3 waves/CU (2048 1-wave blocks) and serialized stage vs
// compute (full vmcnt(0) drain). This version: 128-thread blocks (2 waves, 8
// samples), grid 1024 -> all resident (4 blocks/CU, 8 waves/CU, 34KB LDS).
// Staging is double-buffered in 16-step chunks of 32 global_load_lds; counted
// s_waitcnt vmcnt(32) lets chunk c+1 stay in flight while chunk c computes
// (T3/T4 pattern). vmcnt retirement is in-order, so W(32) always covers the
// chunk issued two stages ago even if the compiler interleaves other loads.

template <int OFF>
__device__ __forceinline__ void glds4(const float* src, float* lds) {
    __builtin_amdgcn_global_load_lds(
        (const __attribute__((address_space(1))) void*)src,
        (__attribute__((address_space(3))) void*)lds, 4, OFF, 0);
}

__device__ __forceinline__ void rnn_step(
    bool upd, v2f pv,
    const v2f (&w0)[16], const v2f (&w1)[16],
    float sb0, float sb1, float& h0, float& h1)
{
    // ---- DPP butterfly all-gather: g[m] = pair (jj ^ GMAP[m]) ----
    v2f g[16];
    g[0] = (v2f){h0, h1};
    g[1] = (v2f){dppf<DPP_XOR1>(g[0][0]), dppf<DPP_XOR1>(g[0][1])};
    g[2] = (v2f){dppf<DPP_XOR2>(g[0][0]), dppf<DPP_XOR2>(g[0][1])};
    g[3] = (v2f){dppf<DPP_XOR2>(g[1][0]), dppf<DPP_XOR2>(g[1][1])};
#pragma unroll
    for (int m = 0; m < 4; m++)
        g[4 + m] = (v2f){dppf<DPP_XOR7>(g[m][0]), dppf<DPP_XOR7>(g[m][1])};
#pragma unroll
    for (int m = 0; m < 8; m++)
        g[8 + m] = (v2f){dppf<DPP_XORF>(g[m][0]), dppf<DPP_XORF>(g[m][1])};

    // ---- 32 pk_fma: rows 2jj and 2jj+1 ----
    v2f a0 = (v2f){0.f, 0.f}, b0 = a0, a1 = a0, b1 = a0;
#pragma unroll
    for (int m = 0; m < 16; m += 2) {
        a0 = __builtin_elementwise_fma(w0[m],     g[m],     a0);
        b0 = __builtin_elementwise_fma(w0[m + 1], g[m + 1], b0);
        a1 = __builtin_elementwise_fma(w1[m],     g[m],     a1);
        b1 = __builtin_elementwise_fma(w1[m + 1], g[m + 1], b1);
    }
    float s0 = sb0 + pv[0] + (a0[0] + a0[1]) + (b0[0] + b0[1]);
    float s1 = sb1 + pv[1] + (a1[0] + a1[1]) + (b1[0] + b1[1]);

    // tanh(s) = 1 - 2/(e^{2s}+1); robust at both extremes, no clamp
    float e0 = __expf(2.f * s0);
    float e1 = __expf(2.f * s1);
    float th0 = 1.f - 2.f * __builtin_amdgcn_rcpf(e0 + 1.f);
    float th1 = 1.f - 2.f * __builtin_amdgcn_rcpf(e1 + 1.f);

    h0 = upd ? th0 : h0;
    h1 = upd ? th1 : h1;
}

__global__ __launch_bounds__(128, 2)
void rnn_kernel(
    const float* __restrict__ proj, const float* __restrict__ bagf,
    const float* __restrict__ W_hh,
    const float* __restrict__ b_ih, const float* __restrict__ b_hh,
    float* __restrict__ out_h)
{
    // per-wave staging buffers: [wave][parity][local step][lane]
    __shared__ float pvx_s[2][2][16][64];     // 16 KB
    __shared__ float pvy_s[2][2][16][64];     // 16 KB
    __shared__ float ids_s[2][4][68];         // [wave][sample][t], padded vs bank 0

    const int tid  = threadIdx.x;
    const int wv   = tid >> 6;
    const int lane = tid & 63;
    const int sl   = lane >> 4;        // sample slot within wave 0..3
    const int jj   = lane & 15;        // owns hidden units 2jj, 2jj+1
    const int b0   = blockIdx.x * 8 + wv * 4;   // wave's first sample

    // gather-position -> pair-xor map (butterfly: xor1, xor2, xor7, xor15)
    const int GMAP[16] = {0,1,2,3, 7,6,5,4, 15,14,13,12,11,10,9,8};

    // weights: w0[m]/w1[m] = rows (2jj, 2jj+1), column pair c = jj ^ GMAP[m]
    v2f w0[16], w1[16];
    const v2f* wr0 = (const v2f*)(W_hh + (2 * jj) * HID);
    const v2f* wr1 = (const v2f*)(W_hh + (2 * jj + 1) * HID);
#pragma unroll
    for (int m = 0; m < 16; m++) {
        const int c = jj ^ GMAP[m];
        w0[m] = wr0[c];
        w1[m] = wr1[c];
    }
    const float sb0 = b_ih[2 * jj]     + b_hh[2 * jj];
    const float sb1 = b_ih[2 * jj + 1] + b_hh[2 * jj + 1];

    // ---- load this wave's 4 samples' bag ids (256 contiguous floats) ----
    {
        const float4 idv = *(const float4*)(bagf + (size_t)b0 * 64 + lane * 4);
        *(float4*)&ids_s[wv][lane >> 4][(lane & 15) * 4] = idv;
    }
    // drain: all prior vmem (ids, weights, biases) retired; lgkm for ds_write.
    asm volatile("s_waitcnt vmcnt(0) lgkmcnt(0)" ::: "memory");
    // wave-private LDS region -> no barrier needed

    const float* ids = &ids_s[wv][sl][0];     // this lane's sample ids
    const float* projb = proj + (jj << 1);    // + row*HID per step

#define STAGE(c)                                                            \
    {                                                                       \
        const int p_ = (c) & 1;                                             \
        _Pragma("unroll")                                                   \
        for (int lt = 0; lt < 16; ++lt) {                                   \
            const int row = (int)ids[(c) * 16 + lt];                        \
            const float* src = projb + row * HID;                           \
            glds4<0>(src, &pvx_s[wv][p_][lt][0]);                           \
            glds4<4>(src, &pvy_s[wv][p_][lt][0]);                           \
        }                                                                   \
    }

#define COMP(c)                                                             \
    {                                                                       \
        const int p_ = (c) & 1;                                             \
        _Pragma("unroll 4")                                                 \
        for (int lt = 0; lt < 16; ++lt) {                                   \
            const float idv = ids[(c) * 16 + lt];                           \
            const v2f pv = (v2f){ pvx_s[wv][p_][lt][lane],                  \
                                  pvy_s[wv][p_][lt][lane] };                \
            rnn_step(idv < 4095.5f, pv, w0, w1, sb0, sb1, h0, h1);          \
        }                                                                   \
    }

    float h0 = 0.f, h1 = 0.f;

    STAGE(0)                                   // 32 in flight
    STAGE(1)                                   // 64 in flight
    asm volatile("s_waitcnt vmcnt(32)" ::: "memory");   // chunk0 landed
    COMP(0)
    STAGE(2)                                   // chunk1 + chunk2 in flight
    asm volatile("s_waitcnt vmcnt(32)" ::: "memory");   // chunk1 landed
    COMP(1)
    STAGE(3)                                   // chunk2 + chunk3 in flight
    asm volatile("s_waitcnt vmcnt(32)" ::: "memory");   // chunk2 landed
    COMP(2)
    asm volatile("s_waitcnt vmcnt(0)" ::: "memory");    // chunk3 landed
    COMP(3)

#undef STAGE
#undef COMP

    ((float2*)(out_h + (size_t)(b0 + sl) * HID))[jj] = make_float2(h0, h1);
}

// ---------------- Fallback RNN (R4 exact) if ws can't hold proj ----------------
__global__ __launch_bounds__(128, 4) void rnn_kernel_noproj(
    const float* __restrict__ emb, const float* __restrict__ bagf,
    const float* __restrict__ W_ih, const float* __restrict__ W_hh,
    const float* __restrict__ b_ih, const float* __restrict__ b_hh,
    float* __restrict__ out_h)
{
    __shared__ float hbuf[4][32];
    const int tid = threadIdx.x;
    const int ib  = tid >> 5;
    const int j   = tid & 31;
    const int b   = blockIdx.x * 4 + ib;

    float wih[EMB];
#pragma unroll
    for (int k = 0; k < EMB; k++) wih[k] = W_ih[j * EMB + k];
    float whh[HID];
#pragma unroll
    for (int k = 0; k < HID; k++) whh[k] = W_hh[j * HID + k];
    const float sbias = b_ih[j] + b_hh[j];

    const float* bp = bagf + (size_t)b * 64;
    unsigned long long m0 = __ballot(bp[j]      < 4095.5f);
    unsigned long long m1 = __ballot(bp[32 + j] < 4095.5f);
    const int half = ib & 1;
    const int len = __popc((unsigned)(m0 >> (half * 32)))
                  + __popc((unsigned)(m1 >> (half * 32)));

    hbuf[ib][j] = 0.f;
    asm volatile("s_waitcnt lgkmcnt(0)" ::: "memory");

    float h = 0.f;
    const float* xb = emb + (size_t)b * (MAXLEN * EMB);
    for (int t = 0; t < MAXLEN; t++) {
        const float4* xp = (const float4*)(xb + t * EMB);
        float4 x0 = xp[0], x1 = xp[1], x2 = xp[2], x3 = xp[3], x4 = xp[4];
        float s = sbias;
        const float4* hb4 = (const float4*)hbuf[ib];
#pragma unroll
        for (int m = 0; m < 8; m++) {
            float4 hv = hb4[m];
            s += whh[4*m+0]*hv.x + whh[4*m+1]*hv.y
               + whh[4*m+2]*hv.z + whh[4*m+3]*hv.w;
        }
        s += wih[0]*x0.x + wih[1]*x0.y + wih[2]*x0.z + wih[3]*x0.w;
        s += wih[4]*x1.x + wih[5]*x1.y + wih[6]*x1.z + wih[7]*x1.w;
        s += wih[8]*x2.x + wih[9]*x2.y + wih[10]*x2.z + wih[11]*x2.w;
        s += wih[12]*x3.x + wih[13]*x3.y + wih[14]*x3.z + wih[15]*x3.w;
        s += wih[16]*x4.x + wih[17]*x4.y + wih[18]*x4.z + wih[19]*x4.w;
        s = fminf(fmaxf(s, -9.f), 9.f);
        float e = __expf(2.f * s);
        float th = (e - 1.f) * __builtin_amdgcn_rcpf(e + 1.f);
        h = (t < len) ? th : h;
        hbuf[ib][j] = h;
        asm volatile("s_waitcnt lgkmcnt(0)" ::: "memory");
    }
    out_h[(size_t)b * HID + j] = h;
}

extern "C" void kernel_launch(void* const* d_in, const int* in_sizes, int n_in,
                              void* d_out, int out_size, void* d_ws, size_t ws_size,
                              hipStream_t stream) {
    const int*   chars     = (const int*)d_in[0];
    const int*   colors    = (const int*)d_in[1];
    const float* emb_table = (const float*)d_in[2];
    const float* W_ih      = (const float*)d_in[3];
    const float* W_hh      = (const float*)d_in[4];
    const float* b_ih      = (const float*)d_in[5];
    const float* b_hh      = (const float*)d_in[6];

    const int B = in_sizes[0] / HW;      // 8192

    float* out     = (float*)d_out;
    float* out_h   = out;                                    // [B, 32]
    float* out_emb = out + (size_t)B * HID;                  // [B, 64, 20]
    float* out_bag = out_emb + (size_t)B * MAXLEN * EMB;     // [B, 64]

    const size_t proj_bytes = (size_t)(PADID + 1) * HID * sizeof(float);

    if (ws_size >= proj_bytes && (B % 8) == 0) {   // ws_size fixed -> same path every call
        float* proj = (float*)d_ws;
        bag_emb_kernel<<<B + PROJ_BLOCKS, 128, 0, stream>>>(
            chars, colors, emb_table, W_ih, out_emb, out_bag, proj, B);
        rnn_kernel<<<B / 8, 128, 0, stream>>>(proj, out_bag, W_hh, b_ih, b_hh, out_h);
    } else {
        bag_emb_kernel<<<B, 128, 0, stream>>>(
            chars, colors, emb_table, W_ih, out_emb, out_bag, (float*)d_ws, B);
        rnn_kernel_noproj<<<B / 4, 128, 0, stream>>>(out_emb, out_bag, W_ih, W_hh,
                                                     b_ih, b_hh, out_h);
    }
}